// Round 2
// baseline (1469.715 us; speedup 1.0000x reference)
//
#include <hip/hip_runtime.h>

// ---------------------------------------------------------------------------
// update_v (PDN-GNN) on MI355X / gfx950.  ALL float I/O is fp32 (per the
// jnp.float32 reference; round-1 NaN came from misreading fp32 as bf16).
//
// Pipeline:
//   1. memset counters
//   2. k_edge       : edge MLP -> ew[E], atomic deg[col], atomic cntC[col]
//   3. k_cntm       : histogram of i[] -> cntM
//   4. k_scan       : exclusive scans (cntC->offC/curC, cntM->offM/curM) + dinv
//   5. k_scatter_col: CSR bucket by col: payload (row, norm)
//   6. k_scatter_m  : CSR bucket by i: payload m
//   7. k_segsum     : Xcat[n,0:128] = sum e2 rows, [128:135]=afe, pad 0
//   8. k_splitw x4  : fp32 W -> bf16 (hi,lo) split, lin_v padded 135->160
//   9+  k_gemm      : 3-term split MFMA GEMM (AhWh + AlWh + AhWl) ~ fp32 exact
//       k_gather    : conv accumulate per node (CSR by col), xw in bf16
//       k_final     : 256 -> 1 dot, fp32 out
//
// Workspace layout (bytes), total 117,865,472:
//   rowp   0            6,400,000
//   normp  6,400,000    6,400,000
//   Xcat   12,800,000   32,000,000   (aliased by s0)
//   s0     12,800,000   51,200,000   (written by lin_up; Xcat dead by then)
//   v1     64,000,000   25,600,000   (aliased by s1)
//   xw     89,600,000   12,800,000   (aliased by s1)
//   s1     64,000,000   51,200,000   (written by lins1; v1+xw dead by then)
//   ew     102,400,000  6,400,000    (inside s1 tail; dead before s1 written)
//   midx   108,800,000  2,400,000    (inside s1 tail; dead before s1 written)
//   cntC   115,200,000  200,000  \
//   cntM   115,400,000  200,000   } memset together
//   deg    115,600,000  200,000  /
//   offC   115,800,000  200,004
//   curC   116,000,256  200,000
//   offM   116,200,256  200,004
//   curM   116,400,512  200,000
//   dinv   116,600,512  200,000
//   Wh     116,800,512  532,480
//   Wl     117,332,992  532,480
// ---------------------------------------------------------------------------

#define Nn 50000
#define Mm 600000
#define Ee 1600000

typedef unsigned short u16;
typedef unsigned int u32;
typedef __attribute__((ext_vector_type(8))) short bh8;   // 8 bf16 = 4 VGPRs
typedef __attribute__((ext_vector_type(4))) float f4;    // 4 fp32 acc

__device__ __forceinline__ float bf2f(u16 u) {
    union { u32 i; float f; } v; v.i = ((u32)u) << 16; return v.f;
}
__device__ __forceinline__ u16 f2bf(float f) {   // RNE, finite inputs
    union { float f; u32 u; } v; v.f = f;
    return (u16)((v.u + 0x7fffu + ((v.u >> 16) & 1u)) >> 16);
}

// --------------------------- edge MLP + degree -----------------------------
__global__ __launch_bounds__(256) void k_edge(
    const float* __restrict__ attr, const int* __restrict__ eidx,
    const float* __restrict__ w1, const float* __restrict__ b1,
    const float* __restrict__ w2, const float* __restrict__ b2,
    float* __restrict__ ew, float* __restrict__ deg, int* __restrict__ cntC)
{
    __shared__ float sW1[64], sB1[8], sW2[8], sB2;
    int t = threadIdx.x;
    if (t < 64) sW1[t] = w1[t];
    if (t < 8) { sB1[t] = b1[t]; sW2[t] = w2[t]; }
    if (t == 0) sB2 = b2[0];
    __syncthreads();
    int e = blockIdx.x * 256 + t;
    if (e >= Ee) return;
    float4 q0 = *(const float4*)(attr + (size_t)e * 8);
    float4 q1 = *(const float4*)(attr + (size_t)e * 8 + 4);
    float a[8] = { q0.x, q0.y, q0.z, q0.w, q1.x, q1.y, q1.z, q1.w };
    float z = sB2;
#pragma unroll
    for (int j = 0; j < 8; ++j) {
        float h = sB1[j];
#pragma unroll
        for (int k = 0; k < 8; ++k) h += a[k] * sW1[j * 8 + k];
        z += fmaxf(h, 0.f) * sW2[j];
    }
    float s = 1.f / (1.f + __expf(-z));
    ew[e] = s;
    int c = eidx[Ee + e];
    atomicAdd(&deg[c], s);
    atomicAdd(&cntC[c], 1);
}

__global__ __launch_bounds__(256) void k_cntm(const int* __restrict__ ii,
                                              int* __restrict__ cnt)
{
    int m = blockIdx.x * 256 + threadIdx.x;
    if (m < Mm) atomicAdd(&cnt[ii[m]], 1);
}

// --------------------------- scans + dinv ----------------------------------
__device__ void scan_one(const int* __restrict__ cnt, int* __restrict__ off,
                         int* __restrict__ cur, int* buf)
{
    int t = threadIdx.x;
    const int CH = (Nn + 1023) >> 10;     // 49
    int lo = t * CH, hi = lo + CH;
    if (hi > Nn) hi = Nn;
    if (lo > Nn) lo = Nn;
    int s = 0;
    for (int i = lo; i < hi; ++i) s += cnt[i];
    __syncthreads();                       // buf free from previous use
    buf[t] = s;
    __syncthreads();
    for (int d = 1; d < 1024; d <<= 1) {   // inclusive Hillis-Steele
        int v = (t >= d) ? buf[t - d] : 0;
        __syncthreads();
        buf[t] += v;
        __syncthreads();
    }
    int base = buf[t] - s;                 // exclusive base of this chunk
    for (int i = lo; i < hi; ++i) { off[i] = base; cur[i] = base; base += cnt[i]; }
    if (t == 1023) off[Nn] = buf[1023];
}

__global__ __launch_bounds__(1024) void k_scan(
    const int* __restrict__ cntC, int* __restrict__ offC, int* __restrict__ curC,
    const int* __restrict__ cntM, int* __restrict__ offM, int* __restrict__ curM,
    const float* __restrict__ deg, float* __restrict__ dinv)
{
    __shared__ int buf[1024];
    scan_one(cntC, offC, curC, buf);
    scan_one(cntM, offM, curM, buf);
    for (int n = threadIdx.x; n < Nn; n += 1024) {
        float d = deg[n];
        dinv[n] = (d > 0.f) ? rsqrtf(fmaxf(d, 1e-30f)) : 0.f;
    }
}

// --------------------------- CSR scatter -----------------------------------
__global__ __launch_bounds__(256) void k_scatter_col(
    const int* __restrict__ eidx, const float* __restrict__ ew,
    const float* __restrict__ dinv, int* __restrict__ cur,
    int* __restrict__ rowp, float* __restrict__ normp)
{
    int e = blockIdx.x * 256 + threadIdx.x;
    if (e >= Ee) return;
    int r = eidx[e], c = eidx[Ee + e];
    float nm = dinv[r] * ew[e] * dinv[c];
    int idx = atomicAdd(&cur[c], 1);       // cur starts at offC -> absolute
    rowp[idx] = r;
    normp[idx] = nm;
}

__global__ __launch_bounds__(256) void k_scatter_m(
    const int* __restrict__ ii, int* __restrict__ cur, int* __restrict__ midx)
{
    int m = blockIdx.x * 256 + threadIdx.x;
    if (m >= Mm) return;
    midx[atomicAdd(&cur[ii[m]], 1)] = m;
}

// --------------------------- e2 segment sum -> Xcat ------------------------
__global__ __launch_bounds__(64) void k_segsum(
    const int* __restrict__ offM, const int* __restrict__ midx,
    const float* __restrict__ e2, const float* __restrict__ afe,
    float* __restrict__ Xcat)
{
    int n = blockIdx.x, lane = threadIdx.x;
    int j0 = offM[n], j1 = offM[n + 1];
    float a0 = 0.f, a1 = 0.f;
    for (int j = j0; j < j1; ++j) {
        int m = midx[j];
        float2 p = *(const float2*)(e2 + (size_t)m * 128 + lane * 2);
        a0 += p.x; a1 += p.y;
    }
    *(float2*)(Xcat + (size_t)n * 160 + lane * 2) = make_float2(a0, a1);
    if (lane < 32) {                       // channels 128..159: afe then pad 0
        int ch = 128 + lane;
        float v = (ch < 135) ? afe[(size_t)n * 7 + (ch - 128)] : 0.f;
        Xcat[(size_t)n * 160 + ch] = v;
    }
}

// --------------------------- weight split (fp32 -> bf16 hi+lo) -------------
__global__ __launch_bounds__(256) void k_splitw(
    const float* __restrict__ src, u16* __restrict__ h, u16* __restrict__ l,
    int rows, int sc, int dc)
{
    int idx = blockIdx.x * 256 + threadIdx.x;
    if (idx >= rows * dc) return;
    int r = idx / dc, c = idx % dc;
    float x = (c < sc) ? src[(size_t)r * sc + c] : 0.f;
    u16 hh = f2bf(x);
    h[idx] = hh;
    l[idx] = f2bf(x - bf2f(hh));
}

// --------------------------- split MFMA GEMM -------------------------------
// Y[M,NO] = op(X[M,K] @ W[NO,K]^T + bias). X fp32 split on the fly; W given
// as bf16 hi/lo. acc += Ah*Wh + Al*Wh + Ah*Wl  (~fp32 exact, err ~2^-18).
// Tile 128x128, BK=32, 4 waves (2x2 of 64x64), 16x16x32 MFMA.
// Layouts (m89/m91): A lane holds A[m=lane&15][k=(lane>>4)*8+j]; B likewise;
// D: col=lane&15, row=(lane>>4)*4+r. flags: 1=relu, 2=store bf16.
__global__ __launch_bounds__(256) void k_gemm(
    const float* __restrict__ X, const u16* __restrict__ Wh,
    const u16* __restrict__ Wl, const float* __restrict__ bias,
    void* __restrict__ Y, int M, int K, int NO, int flags)
{
    __shared__ __align__(16) u16 Ah[128][40];   // +8 pad (2-way banks: free)
    __shared__ __align__(16) u16 Al[128][40];
    __shared__ __align__(16) u16 Bh[128][40];
    __shared__ __align__(16) u16 Bl[128][40];
    const int t = threadIdx.x;
    const int m0 = blockIdx.x * 128, n0 = blockIdx.y * 128;
    const int lane = t & 63, wv = t >> 6;
    const int wm = (wv >> 1) * 64, wn = (wv & 1) * 64;
    const int lr = lane & 15, lq = lane >> 4;
    const int srow = t >> 1, skc = (t & 1) * 16;   // staging: 2 thr / row
    const bool aok = (m0 + srow) < M;
    const float* Xp = X + (size_t)(m0 + srow) * K + skc;
    const u16* Whp = Wh + (size_t)(n0 + srow) * K + skc;
    const u16* Wlp = Wl + (size_t)(n0 + srow) * K + skc;
    f4 acc[4][4] = {};

    for (int k0 = 0; k0 < K; k0 += 32) {
        float av[16];
#pragma unroll
        for (int g = 0; g < 4; ++g) {
            float4 v = make_float4(0.f, 0.f, 0.f, 0.f);
            if (aok) v = *(const float4*)(Xp + k0 + g * 4);
            av[g * 4 + 0] = v.x; av[g * 4 + 1] = v.y;
            av[g * 4 + 2] = v.z; av[g * 4 + 3] = v.w;
        }
        uint4 bh0 = *(const uint4*)(Whp + k0);
        uint4 bh1 = *(const uint4*)(Whp + k0 + 8);
        uint4 bl0 = *(const uint4*)(Wlp + k0);
        uint4 bl1 = *(const uint4*)(Wlp + k0 + 8);
        __syncthreads();                    // LDS free from previous reads
#pragma unroll
        for (int g = 0; g < 4; ++g) {       // split fp32 -> bf16 hi + lo
            union { u16 s[4]; uint2 d; } h, l;
#pragma unroll
            for (int j = 0; j < 4; ++j) {
                float x = av[g * 4 + j];
                u16 hh = f2bf(x);
                h.s[j] = hh; l.s[j] = f2bf(x - bf2f(hh));
            }
            *(uint2*)&Ah[srow][skc + g * 4] = h.d;
            *(uint2*)&Al[srow][skc + g * 4] = l.d;
        }
        *(uint4*)&Bh[srow][skc]     = bh0;
        *(uint4*)&Bh[srow][skc + 8] = bh1;
        *(uint4*)&Bl[srow][skc]     = bl0;
        *(uint4*)&Bl[srow][skc + 8] = bl1;
        __syncthreads();
        bh8 fah[4], fal[4], fbh[4], fbl[4];
#pragma unroll
        for (int i = 0; i < 4; ++i) {
            fah[i] = *(const bh8*)&Ah[wm + i * 16 + lr][lq * 8];
            fal[i] = *(const bh8*)&Al[wm + i * 16 + lr][lq * 8];
            fbh[i] = *(const bh8*)&Bh[wn + i * 16 + lr][lq * 8];
            fbl[i] = *(const bh8*)&Bl[wn + i * 16 + lr][lq * 8];
        }
#pragma unroll
        for (int mi = 0; mi < 4; ++mi)
#pragma unroll
            for (int ni = 0; ni < 4; ++ni) {
                acc[mi][ni] = __builtin_amdgcn_mfma_f32_16x16x32_bf16(
                    fah[mi], fbh[ni], acc[mi][ni], 0, 0, 0);
                acc[mi][ni] = __builtin_amdgcn_mfma_f32_16x16x32_bf16(
                    fal[mi], fbh[ni], acc[mi][ni], 0, 0, 0);
                acc[mi][ni] = __builtin_amdgcn_mfma_f32_16x16x32_bf16(
                    fah[mi], fbl[ni], acc[mi][ni], 0, 0, 0);
            }
    }
#pragma unroll
    for (int ni = 0; ni < 4; ++ni) {
        int gn = n0 + wn + ni * 16 + lr;
        float bv = bias ? bias[gn] : 0.f;
#pragma unroll
        for (int mi = 0; mi < 4; ++mi) {
#pragma unroll
            for (int r = 0; r < 4; ++r) {
                int gm = m0 + wm + mi * 16 + lq * 4 + r;
                if (gm < M) {
                    float v = acc[mi][ni][r] + bv;
                    if (flags & 1) v = fmaxf(v, 0.f);
                    if (flags & 2) ((u16*)Y)[(size_t)gm * NO + gn] = f2bf(v);
                    else           ((float*)Y)[(size_t)gm * NO + gn] = v;
                }
            }
        }
    }
}

// --------------------------- conv gather (CSR by col) ----------------------
__global__ __launch_bounds__(64) void k_gather(
    const int* __restrict__ off, const int* __restrict__ rowp,
    const float* __restrict__ normp, const u16* __restrict__ xw,
    float* __restrict__ out, int relu)
{
    int n = blockIdx.x, lane = threadIdx.x;
    int j0 = off[n], j1 = off[n + 1];
    float a0 = 0.f, a1 = 0.f;
    for (int j = j0; j < j1; ++j) {
        int r = rowp[j];                    // block-uniform -> scalar load
        float w = normp[j];
        u32 p = *(const u32*)(xw + (size_t)r * 128 + lane * 2);
        a0 += w * bf2f((u16)(p & 0xffff));
        a1 += w * bf2f((u16)(p >> 16));
    }
    if (relu) { a0 = fmaxf(a0, 0.f); a1 = fmaxf(a1, 0.f); }
    *(float2*)(out + (size_t)n * 128 + lane * 2) = make_float2(a0, a1);
}

// --------------------------- final 256 -> 1 --------------------------------
__global__ __launch_bounds__(256) void k_final(
    const float* __restrict__ S, const float* __restrict__ lw,
    float* __restrict__ out)
{
    __shared__ float w[256];
    int t = threadIdx.x;
    w[t] = lw[t];
    __syncthreads();
    int n = blockIdx.x * 4 + (t >> 6);
    int lane = t & 63;
    if (n >= Nn) return;
    float s = 0.f;
#pragma unroll
    for (int k = 0; k < 4; ++k)
        s += S[(size_t)n * 256 + lane + k * 64] * w[lane + k * 64];
#pragma unroll
    for (int d = 32; d >= 1; d >>= 1) s += __shfl_xor(s, d, 64);
    if (lane == 0) out[n] = s;
}

// ---------------------------------------------------------------------------
extern "C" void kernel_launch(void* const* d_in, const int* in_sizes, int n_in,
                              void* d_out, int out_size, void* d_ws, size_t ws_size,
                              hipStream_t stream)
{
    (void)in_sizes; (void)n_in; (void)out_size; (void)ws_size;
    const float* e2       = (const float*)d_in[0];
    const int*   iidx     = (const int*)d_in[1];
    const float* afe      = (const float*)d_in[2];
    const int*   bei      = (const int*)d_in[3];
    const float* battr    = (const float*)d_in[4];
    const float* lin_v_w  = (const float*)d_in[5];
    const float* lin_v_b  = (const float*)d_in[6];
    const float* conv_w   = (const float*)d_in[7];
    const float* w1       = (const float*)d_in[8];
    const float* b1       = (const float*)d_in[9];
    const float* w2       = (const float*)d_in[10];
    const float* b2       = (const float*)d_in[11];
    const float* lin_up_w = (const float*)d_in[12];
    const float* lin_up_b = (const float*)d_in[13];
    const float* lins_w   = (const float*)d_in[14];
    const float* lins_b   = (const float*)d_in[15];
    const float* lin_w    = (const float*)d_in[16];

    char* ws = (char*)d_ws;
    int*   rowp  = (int*)  (ws + 0);
    float* normp = (float*)(ws + 6400000);
    float* Xcat  = (float*)(ws + 12800000);
    float* s0    = (float*)(ws + 12800000);     // alias (Xcat dead by lin_up)
    float* v1    = (float*)(ws + 64000000);
    u16*   xw    = (u16*)  (ws + 89600000);
    float* s1    = (float*)(ws + 64000000);     // alias (v1,xw dead by lins1)
    float* ew    = (float*)(ws + 102400000);    // s1 tail; dead early
    int*   midx  = (int*)  (ws + 108800000);    // s1 tail; dead early
    int*   cntC  = (int*)  (ws + 115200000);
    int*   cntM  = (int*)  (ws + 115400000);
    float* deg   = (float*)(ws + 115600000);
    int*   offC  = (int*)  (ws + 115800000);
    int*   curC  = (int*)  (ws + 116000256);
    int*   offM  = (int*)  (ws + 116200256);
    int*   curM  = (int*)  (ws + 116400512);
    float* dinv  = (float*)(ws + 116600512);
    u16*   Wh    = (u16*)  (ws + 116800512);    // 266,240 elements
    u16*   Wl    = (u16*)  (ws + 117332992);

    // Wh/Wl element offsets per matrix:
    const int oWv = 0, oConv = 20480, oLup = 36864, oLins = 69632;

    hipMemsetAsync(ws + 115200000, 0, 3 * Nn * 4, stream);   // cntC,cntM,deg

    k_edge<<<(Ee + 255) / 256, 256, 0, stream>>>(battr, bei, w1, b1, w2, b2,
                                                 ew, deg, cntC);
    k_cntm<<<(Mm + 255) / 256, 256, 0, stream>>>(iidx, cntM);
    k_scan<<<1, 1024, 0, stream>>>(cntC, offC, curC, cntM, offM, curM, deg, dinv);
    k_scatter_col<<<(Ee + 255) / 256, 256, 0, stream>>>(bei, ew, dinv, curC,
                                                        rowp, normp);
    k_scatter_m<<<(Mm + 255) / 256, 256, 0, stream>>>(iidx, curM, midx);
    k_segsum<<<Nn, 64, 0, stream>>>(offM, midx, e2, afe, Xcat);

    k_splitw<<<(128 * 160 + 255) / 256, 256, 0, stream>>>(
        lin_v_w, Wh + oWv, Wl + oWv, 128, 135, 160);
    k_splitw<<<(128 * 128 + 255) / 256, 256, 0, stream>>>(
        conv_w, Wh + oConv, Wl + oConv, 128, 128, 128);
    k_splitw<<<(256 * 128 + 255) / 256, 256, 0, stream>>>(
        lin_up_w, Wh + oLup, Wl + oLup, 256, 128, 128);
    k_splitw<<<(768 * 256 + 255) / 256, 256, 0, stream>>>(
        lins_w, Wh + oLins, Wl + oLins, 768, 256, 256);

#define GEMM(Xp, WO, Bp, Yp, M_, K_, NO_, FL_)                                \
    k_gemm<<<dim3(((M_) + 127) / 128, (NO_) / 128), 256, 0, stream>>>(        \
        (const float*)(Xp), Wh + (WO), Wl + (WO), (const float*)(Bp),         \
        (void*)(Yp), M_, K_, NO_, FL_)

    GEMM(Xcat, oWv, lin_v_b, v1, Nn, 160, 128, 0);            // v1 fp32
    GEMM(v1, oConv, nullptr, xw, Nn, 128, 128, 2);            // xw1 bf16
    k_gather<<<Nn, 64, 0, stream>>>(offC, rowp, normp, xw, v1, 0);   // c1
    GEMM(v1, oConv, nullptr, xw, Nn, 128, 128, 2);            // xw2 bf16
    k_gather<<<Nn, 64, 0, stream>>>(offC, rowp, normp, xw, v1, 1);   // c2+relu
    GEMM(v1, oLup, lin_up_b, s0, Nn, 128, 256, 0);            // lin_up
    GEMM(s0, oLins + 0 * 65536, lins_b + 0,   s1, Nn, 256, 256, 1);
    GEMM(s1, oLins + 1 * 65536, lins_b + 256, s0, Nn, 256, 256, 1);
    GEMM(s0, oLins + 2 * 65536, lins_b + 512, s1, Nn, 256, 256, 1);
    k_final<<<(Nn + 3) / 4, 256, 0, stream>>>(s1, lin_w, (float*)d_out);
#undef GEMM
}

// Round 3
// 1235.171 us; speedup vs baseline: 1.1899x; 1.1899x over previous
//
#include <hip/hip_runtime.h>

// ---------------------------------------------------------------------------
// update_v (PDN-GNN) on MI355X / gfx950.  All float I/O fp32.
//
// R3 changes vs R2 (passed, 1469 us, absmax 3.7e-4):
//  - k_scan (246 us, single-block) -> 3-phase multi-block scan (kA/kB/kC)
//  - (row,norm) packed into one int2 payload (1x8B scattered store, not 2x4B)
//  - k_gather / k_segsum: wave-per-node in 256-thr blocks (full 32-wave
//    residency vs 16 with 64-thr blocks) + depth-2 software pipeline
// GEMM path and numerics unchanged (3-term bf16-split MFMA ~ fp32 exact).
//
// Workspace layout (bytes), total 117,867,264:
//   edgep  0            12,800,000   (int2 row+norm per edge, CSR by col)
//   Xcat   12,800,000   32,000,000   (aliased by s0)
//   s0     12,800,000   51,200,000   (written by lin_up; Xcat dead by then)
//   v1     64,000,000   25,600,000   (aliased by s1)
//   xw     89,600,000   12,800,000   (aliased by s1)
//   s1     64,000,000   51,200,000   (written by lins1; v1+xw dead by then)
//   ew     102,400,000  6,400,000    (s1 tail; dead before s1 written)
//   midx   108,800,000  2,400,000    (s1 tail; dead before s1 written)
//   cntC   115,200,000  200,000  \
//   cntM   115,400,000  200,000   } memset together
//   deg    115,600,000  200,000  /
//   offC   115,800,000  200,004
//   curC   116,000,256  200,000
//   offM   116,200,256  200,004
//   curM   116,400,512  200,000
//   dinv   116,600,512  200,000
//   Wh     116,800,512  532,480
//   Wl     117,332,992  532,480
//   partC  117,865,472  784
//   partM  117,866,368  784
// ---------------------------------------------------------------------------

#define Nn 50000
#define Mm 600000
#define Ee 1600000
#define NB 196          // ceil(Nn/256)

typedef unsigned short u16;
typedef unsigned int u32;
typedef __attribute__((ext_vector_type(8))) short bh8;   // 8 bf16 = 4 VGPRs
typedef __attribute__((ext_vector_type(4))) float f4;    // 4 fp32 acc

__device__ __forceinline__ float bf2f(u16 u) {
    union { u32 i; float f; } v; v.i = ((u32)u) << 16; return v.f;
}
__device__ __forceinline__ u16 f2bf(float f) {   // RNE, finite inputs
    union { float f; u32 u; } v; v.f = f;
    return (u16)((v.u + 0x7fffu + ((v.u >> 16) & 1u)) >> 16);
}

// --------------------------- edge MLP + degree -----------------------------
__global__ __launch_bounds__(256) void k_edge(
    const float* __restrict__ attr, const int* __restrict__ eidx,
    const float* __restrict__ w1, const float* __restrict__ b1,
    const float* __restrict__ w2, const float* __restrict__ b2,
    float* __restrict__ ew, float* __restrict__ deg, int* __restrict__ cntC)
{
    __shared__ float sW1[64], sB1[8], sW2[8], sB2;
    int t = threadIdx.x;
    if (t < 64) sW1[t] = w1[t];
    if (t < 8) { sB1[t] = b1[t]; sW2[t] = w2[t]; }
    if (t == 0) sB2 = b2[0];
    __syncthreads();
    int e = blockIdx.x * 256 + t;
    if (e >= Ee) return;
    float4 q0 = *(const float4*)(attr + (size_t)e * 8);
    float4 q1 = *(const float4*)(attr + (size_t)e * 8 + 4);
    float a[8] = { q0.x, q0.y, q0.z, q0.w, q1.x, q1.y, q1.z, q1.w };
    float z = sB2;
#pragma unroll
    for (int j = 0; j < 8; ++j) {
        float h = sB1[j];
#pragma unroll
        for (int k = 0; k < 8; ++k) h += a[k] * sW1[j * 8 + k];
        z += fmaxf(h, 0.f) * sW2[j];
    }
    float s = 1.f / (1.f + __expf(-z));
    ew[e] = s;
    int c = eidx[Ee + e];
    atomicAdd(&deg[c], s);
    atomicAdd(&cntC[c], 1);
}

__global__ __launch_bounds__(256) void k_cntm(const int* __restrict__ ii,
                                              int* __restrict__ cnt)
{
    int m = blockIdx.x * 256 + threadIdx.x;
    if (m < Mm) atomicAdd(&cnt[ii[m]], 1);
}

// --------------------- 3-phase multi-block exclusive scan ------------------
// kA: per-block local exclusive scan into `loc`, block total into `part`
__global__ __launch_bounds__(256) void k_scanA(
    const int* __restrict__ cnt, int* __restrict__ loc, int* __restrict__ part)
{
    __shared__ int buf[256];
    int t = threadIdx.x, i = blockIdx.x * 256 + t;
    int v = (i < Nn) ? cnt[i] : 0;
    buf[t] = v;
    __syncthreads();
#pragma unroll
    for (int d = 1; d < 256; d <<= 1) {
        int x = (t >= d) ? buf[t - d] : 0;
        __syncthreads();
        buf[t] += x;
        __syncthreads();
    }
    if (i < Nn) loc[i] = buf[t] - v;        // local exclusive
    if (t == 255) part[blockIdx.x] = buf[255];
}

// kB: exclusive-scan the NB partials (block 0 -> pA, block 1 -> pB)
__global__ __launch_bounds__(256) void k_scanB(int* __restrict__ pA,
                                               int* __restrict__ pB)
{
    int* p = blockIdx.x ? pB : pA;
    __shared__ int buf[256];
    int t = threadIdx.x;
    int v = (t < NB) ? p[t] : 0;
    buf[t] = v;
    __syncthreads();
#pragma unroll
    for (int d = 1; d < 256; d <<= 1) {
        int x = (t >= d) ? buf[t - d] : 0;
        __syncthreads();
        buf[t] += x;
        __syncthreads();
    }
    if (t < NB) p[t] = buf[t] - v;
}

// kC: off = loc + part[b]; cur = off; off[Nn] = total; optional dinv
__global__ __launch_bounds__(256) void k_scanC(
    const int* __restrict__ cnt, const int* __restrict__ part,
    int* __restrict__ off, int* __restrict__ cur,
    const float* __restrict__ deg, float* __restrict__ dinv)
{
    int t = threadIdx.x, i = blockIdx.x * 256 + t;
    if (i >= Nn) return;
    int v = off[i] + part[blockIdx.x];
    off[i] = v;
    cur[i] = v;
    if (i == Nn - 1) off[Nn] = v + cnt[i];
    if (dinv) {
        float d = deg[i];
        dinv[i] = (d > 0.f) ? rsqrtf(fmaxf(d, 1e-30f)) : 0.f;
    }
}

// --------------------------- CSR scatter -----------------------------------
__global__ __launch_bounds__(256) void k_scatter_col(
    const int* __restrict__ eidx, const float* __restrict__ ew,
    const float* __restrict__ dinv, int* __restrict__ cur,
    int2* __restrict__ edgep)
{
    int e = blockIdx.x * 256 + threadIdx.x;
    if (e >= Ee) return;
    int r = eidx[e], c = eidx[Ee + e];
    float nm = dinv[r] * ew[e] * dinv[c];
    int idx = atomicAdd(&cur[c], 1);       // cur starts at offC -> absolute
    edgep[idx] = make_int2(r, __float_as_int(nm));
}

__global__ __launch_bounds__(256) void k_scatter_m(
    const int* __restrict__ ii, int* __restrict__ cur, int* __restrict__ midx)
{
    int m = blockIdx.x * 256 + threadIdx.x;
    if (m >= Mm) return;
    midx[atomicAdd(&cur[ii[m]], 1)] = m;
}

// --------------------------- e2 segment sum -> Xcat ------------------------
// wave-per-node, 4 nodes / 256-thr block, depth-2 pipelined row loads
__global__ __launch_bounds__(256) void k_segsum(
    const int* __restrict__ offM, const int* __restrict__ midx,
    const float* __restrict__ e2, const float* __restrict__ afe,
    float* __restrict__ Xcat)
{
    int wv = threadIdx.x >> 6, lane = threadIdx.x & 63;
    int n = blockIdx.x * 4 + wv;
    if (n >= Nn) return;
    int j0 = offM[n], j1 = offM[n + 1];
    float a0 = 0.f, a1 = 0.f;
    int j = j0;
    if (j < j1) {
        int m = midx[j];
        float2 p = *(const float2*)(e2 + (size_t)m * 128 + lane * 2);
        for (++j; j < j1; ++j) {
            int m2 = midx[j];
            float2 p2 = *(const float2*)(e2 + (size_t)m2 * 128 + lane * 2);
            a0 += p.x; a1 += p.y;
            p = p2;
        }
        a0 += p.x; a1 += p.y;
    }
    *(float2*)(Xcat + (size_t)n * 160 + lane * 2) = make_float2(a0, a1);
    if (lane < 32) {                       // channels 128..159: afe then pad 0
        int ch = 128 + lane;
        float v = (ch < 135) ? afe[(size_t)n * 7 + (ch - 128)] : 0.f;
        Xcat[(size_t)n * 160 + ch] = v;
    }
}

// --------------------------- weight split (fp32 -> bf16 hi+lo) -------------
__global__ __launch_bounds__(256) void k_splitw(
    const float* __restrict__ src, u16* __restrict__ h, u16* __restrict__ l,
    int rows, int sc, int dc)
{
    int idx = blockIdx.x * 256 + threadIdx.x;
    if (idx >= rows * dc) return;
    int r = idx / dc, c = idx % dc;
    float x = (c < sc) ? src[(size_t)r * sc + c] : 0.f;
    u16 hh = f2bf(x);
    h[idx] = hh;
    l[idx] = f2bf(x - bf2f(hh));
}

// --------------------------- split MFMA GEMM -------------------------------
// Y[M,NO] = op(X[M,K] @ W[NO,K]^T + bias). X fp32 split on the fly; W given
// as bf16 hi/lo. acc += Ah*Wh + Al*Wh + Ah*Wl  (~fp32 exact, err ~2^-18).
// Tile 128x128, BK=32, 4 waves (2x2 of 64x64), 16x16x32 MFMA.
// Layouts (m89/m91): A lane holds A[m=lane&15][k=(lane>>4)*8+j]; B likewise;
// D: col=lane&15, row=(lane>>4)*4+r. flags: 1=relu, 2=store bf16.
__global__ __launch_bounds__(256) void k_gemm(
    const float* __restrict__ X, const u16* __restrict__ Wh,
    const u16* __restrict__ Wl, const float* __restrict__ bias,
    void* __restrict__ Y, int M, int K, int NO, int flags)
{
    __shared__ __align__(16) u16 Ah[128][40];   // +8 pad (2-way banks: free)
    __shared__ __align__(16) u16 Al[128][40];
    __shared__ __align__(16) u16 Bh[128][40];
    __shared__ __align__(16) u16 Bl[128][40];
    const int t = threadIdx.x;
    const int m0 = blockIdx.x * 128, n0 = blockIdx.y * 128;
    const int lane = t & 63, wv = t >> 6;
    const int wm = (wv >> 1) * 64, wn = (wv & 1) * 64;
    const int lr = lane & 15, lq = lane >> 4;
    const int srow = t >> 1, skc = (t & 1) * 16;   // staging: 2 thr / row
    const bool aok = (m0 + srow) < M;
    const float* Xp = X + (size_t)(m0 + srow) * K + skc;
    const u16* Whp = Wh + (size_t)(n0 + srow) * K + skc;
    const u16* Wlp = Wl + (size_t)(n0 + srow) * K + skc;
    f4 acc[4][4] = {};

    for (int k0 = 0; k0 < K; k0 += 32) {
        float av[16];
#pragma unroll
        for (int g = 0; g < 4; ++g) {
            float4 v = make_float4(0.f, 0.f, 0.f, 0.f);
            if (aok) v = *(const float4*)(Xp + k0 + g * 4);
            av[g * 4 + 0] = v.x; av[g * 4 + 1] = v.y;
            av[g * 4 + 2] = v.z; av[g * 4 + 3] = v.w;
        }
        uint4 bh0 = *(const uint4*)(Whp + k0);
        uint4 bh1 = *(const uint4*)(Whp + k0 + 8);
        uint4 bl0 = *(const uint4*)(Wlp + k0);
        uint4 bl1 = *(const uint4*)(Wlp + k0 + 8);
        __syncthreads();                    // LDS free from previous reads
#pragma unroll
        for (int g = 0; g < 4; ++g) {       // split fp32 -> bf16 hi + lo
            union { u16 s[4]; uint2 d; } h, l;
#pragma unroll
            for (int j = 0; j < 4; ++j) {
                float x = av[g * 4 + j];
                u16 hh = f2bf(x);
                h.s[j] = hh; l.s[j] = f2bf(x - bf2f(hh));
            }
            *(uint2*)&Ah[srow][skc + g * 4] = h.d;
            *(uint2*)&Al[srow][skc + g * 4] = l.d;
        }
        *(uint4*)&Bh[srow][skc]     = bh0;
        *(uint4*)&Bh[srow][skc + 8] = bh1;
        *(uint4*)&Bl[srow][skc]     = bl0;
        *(uint4*)&Bl[srow][skc + 8] = bl1;
        __syncthreads();
        bh8 fah[4], fal[4], fbh[4], fbl[4];
#pragma unroll
        for (int i = 0; i < 4; ++i) {
            fah[i] = *(const bh8*)&Ah[wm + i * 16 + lr][lq * 8];
            fal[i] = *(const bh8*)&Al[wm + i * 16 + lr][lq * 8];
            fbh[i] = *(const bh8*)&Bh[wn + i * 16 + lr][lq * 8];
            fbl[i] = *(const bh8*)&Bl[wn + i * 16 + lr][lq * 8];
        }
#pragma unroll
        for (int mi = 0; mi < 4; ++mi)
#pragma unroll
            for (int ni = 0; ni < 4; ++ni) {
                acc[mi][ni] = __builtin_amdgcn_mfma_f32_16x16x32_bf16(
                    fah[mi], fbh[ni], acc[mi][ni], 0, 0, 0);
                acc[mi][ni] = __builtin_amdgcn_mfma_f32_16x16x32_bf16(
                    fal[mi], fbh[ni], acc[mi][ni], 0, 0, 0);
                acc[mi][ni] = __builtin_amdgcn_mfma_f32_16x16x32_bf16(
                    fah[mi], fbl[ni], acc[mi][ni], 0, 0, 0);
            }
    }
#pragma unroll
    for (int ni = 0; ni < 4; ++ni) {
        int gn = n0 + wn + ni * 16 + lr;
        float bv = bias ? bias[gn] : 0.f;
#pragma unroll
        for (int mi = 0; mi < 4; ++mi) {
#pragma unroll
            for (int r = 0; r < 4; ++r) {
                int gm = m0 + wm + mi * 16 + lq * 4 + r;
                if (gm < M) {
                    float v = acc[mi][ni][r] + bv;
                    if (flags & 1) v = fmaxf(v, 0.f);
                    if (flags & 2) ((u16*)Y)[(size_t)gm * NO + gn] = f2bf(v);
                    else           ((float*)Y)[(size_t)gm * NO + gn] = v;
                }
            }
        }
    }
}

// --------------------------- conv gather (CSR by col) ----------------------
// wave-per-node, 4 nodes / 256-thr block, depth-2 pipelined loads
__global__ __launch_bounds__(256) void k_gather(
    const int* __restrict__ off, const int2* __restrict__ edgep,
    const u16* __restrict__ xw, float* __restrict__ out, int relu)
{
    int wv = threadIdx.x >> 6, lane = threadIdx.x & 63;
    int n = blockIdx.x * 4 + wv;
    if (n >= Nn) return;
    int j0 = off[n], j1 = off[n + 1];
    float a0 = 0.f, a1 = 0.f;
    int j = j0;
    if (j < j1) {
        int2 ep = edgep[j];
        u32 p = *(const u32*)(xw + (size_t)ep.x * 128 + lane * 2);
        for (++j; j < j1; ++j) {
            int2 ep2 = edgep[j];
            u32 p2 = *(const u32*)(xw + (size_t)ep2.x * 128 + lane * 2);
            float w = __int_as_float(ep.y);
            a0 += w * bf2f((u16)(p & 0xffff));
            a1 += w * bf2f((u16)(p >> 16));
            ep = ep2; p = p2;
        }
        float w = __int_as_float(ep.y);
        a0 += w * bf2f((u16)(p & 0xffff));
        a1 += w * bf2f((u16)(p >> 16));
    }
    if (relu) { a0 = fmaxf(a0, 0.f); a1 = fmaxf(a1, 0.f); }
    *(float2*)(out + (size_t)n * 128 + lane * 2) = make_float2(a0, a1);
}

// --------------------------- final 256 -> 1 --------------------------------
__global__ __launch_bounds__(256) void k_final(
    const float* __restrict__ S, const float* __restrict__ lw,
    float* __restrict__ out)
{
    __shared__ float w[256];
    int t = threadIdx.x;
    w[t] = lw[t];
    __syncthreads();
    int n = blockIdx.x * 4 + (t >> 6);
    int lane = t & 63;
    if (n >= Nn) return;
    float s = 0.f;
#pragma unroll
    for (int k = 0; k < 4; ++k)
        s += S[(size_t)n * 256 + lane + k * 64] * w[lane + k * 64];
#pragma unroll
    for (int d = 32; d >= 1; d >>= 1) s += __shfl_xor(s, d, 64);
    if (lane == 0) out[n] = s;
}

// ---------------------------------------------------------------------------
extern "C" void kernel_launch(void* const* d_in, const int* in_sizes, int n_in,
                              void* d_out, int out_size, void* d_ws, size_t ws_size,
                              hipStream_t stream)
{
    (void)in_sizes; (void)n_in; (void)out_size; (void)ws_size;
    const float* e2       = (const float*)d_in[0];
    const int*   iidx     = (const int*)d_in[1];
    const float* afe      = (const float*)d_in[2];
    const int*   bei      = (const int*)d_in[3];
    const float* battr    = (const float*)d_in[4];
    const float* lin_v_w  = (const float*)d_in[5];
    const float* lin_v_b  = (const float*)d_in[6];
    const float* conv_w   = (const float*)d_in[7];
    const float* w1       = (const float*)d_in[8];
    const float* b1       = (const float*)d_in[9];
    const float* w2       = (const float*)d_in[10];
    const float* b2       = (const float*)d_in[11];
    const float* lin_up_w = (const float*)d_in[12];
    const float* lin_up_b = (const float*)d_in[13];
    const float* lins_w   = (const float*)d_in[14];
    const float* lins_b   = (const float*)d_in[15];
    const float* lin_w    = (const float*)d_in[16];

    char* ws = (char*)d_ws;
    int2*  edgep = (int2*) (ws + 0);
    float* Xcat  = (float*)(ws + 12800000);
    float* s0    = (float*)(ws + 12800000);     // alias (Xcat dead by lin_up)
    float* v1    = (float*)(ws + 64000000);
    u16*   xw    = (u16*)  (ws + 89600000);
    float* s1    = (float*)(ws + 64000000);     // alias (v1,xw dead by lins1)
    float* ew    = (float*)(ws + 102400000);    // s1 tail; dead early
    int*   midx  = (int*)  (ws + 108800000);    // s1 tail; dead early
    int*   cntC  = (int*)  (ws + 115200000);
    int*   cntM  = (int*)  (ws + 115400000);
    float* deg   = (float*)(ws + 115600000);
    int*   offC  = (int*)  (ws + 115800000);
    int*   curC  = (int*)  (ws + 116000256);
    int*   offM  = (int*)  (ws + 116200256);
    int*   curM  = (int*)  (ws + 116400512);
    float* dinv  = (float*)(ws + 116600512);
    u16*   Wh    = (u16*)  (ws + 116800512);    // 266,240 elements
    u16*   Wl    = (u16*)  (ws + 117332992);
    int*   partC = (int*)  (ws + 117865472);
    int*   partM = (int*)  (ws + 117866368);

    // Wh/Wl element offsets per matrix:
    const int oWv = 0, oConv = 20480, oLup = 36864, oLins = 69632;

    hipMemsetAsync(ws + 115200000, 0, 3 * Nn * 4, stream);   // cntC,cntM,deg

    k_edge<<<(Ee + 255) / 256, 256, 0, stream>>>(battr, bei, w1, b1, w2, b2,
                                                 ew, deg, cntC);
    k_cntm<<<(Mm + 255) / 256, 256, 0, stream>>>(iidx, cntM);
    k_scanA<<<NB, 256, 0, stream>>>(cntC, offC, partC);
    k_scanA<<<NB, 256, 0, stream>>>(cntM, offM, partM);
    k_scanB<<<2, 256, 0, stream>>>(partC, partM);
    k_scanC<<<NB, 256, 0, stream>>>(cntC, partC, offC, curC, deg, dinv);
    k_scanC<<<NB, 256, 0, stream>>>(cntM, partM, offM, curM, nullptr, nullptr);
    k_scatter_col<<<(Ee + 255) / 256, 256, 0, stream>>>(bei, ew, dinv, curC,
                                                        edgep);
    k_scatter_m<<<(Mm + 255) / 256, 256, 0, stream>>>(iidx, curM, midx);
    k_segsum<<<(Nn + 3) / 4, 256, 0, stream>>>(offM, midx, e2, afe, Xcat);

    k_splitw<<<(128 * 160 + 255) / 256, 256, 0, stream>>>(
        lin_v_w, Wh + oWv, Wl + oWv, 128, 135, 160);
    k_splitw<<<(128 * 128 + 255) / 256, 256, 0, stream>>>(
        conv_w, Wh + oConv, Wl + oConv, 128, 128, 128);
    k_splitw<<<(256 * 128 + 255) / 256, 256, 0, stream>>>(
        lin_up_w, Wh + oLup, Wl + oLup, 256, 128, 128);
    k_splitw<<<(768 * 256 + 255) / 256, 256, 0, stream>>>(
        lins_w, Wh + oLins, Wl + oLins, 768, 256, 256);

#define GEMM(Xp, WO, Bp, Yp, M_, K_, NO_, FL_)                                \
    k_gemm<<<dim3(((M_) + 127) / 128, (NO_) / 128), 256, 0, stream>>>(        \
        (const float*)(Xp), Wh + (WO), Wl + (WO), (const float*)(Bp),         \
        (void*)(Yp), M_, K_, NO_, FL_)

    GEMM(Xcat, oWv, lin_v_b, v1, Nn, 160, 128, 0);            // v1 fp32
    GEMM(v1, oConv, nullptr, xw, Nn, 128, 128, 2);            // xw1 bf16
    k_gather<<<(Nn + 3) / 4, 256, 0, stream>>>(offC, edgep, xw, v1, 0);
    GEMM(v1, oConv, nullptr, xw, Nn, 128, 128, 2);            // xw2 bf16
    k_gather<<<(Nn + 3) / 4, 256, 0, stream>>>(offC, edgep, xw, v1, 1);
    GEMM(v1, oLup, lin_up_b, s0, Nn, 128, 256, 0);            // lin_up
    GEMM(s0, oLins + 0 * 65536, lins_b + 0,   s1, Nn, 256, 256, 1);
    GEMM(s1, oLins + 1 * 65536, lins_b + 256, s0, Nn, 256, 256, 1);
    GEMM(s0, oLins + 2 * 65536, lins_b + 512, s1, Nn, 256, 256, 1);
    k_final<<<(Nn + 3) / 4, 256, 0, stream>>>(s1, lin_w, (float*)d_out);
#undef GEMM
}